// Round 11
// baseline (190.576 us; speedup 1.0000x reference)
//
#include <hip/hip_runtime.h>
#include <hip/hip_cooperative_groups.h>

namespace cg = cooperative_groups;

#define D_FEAT 128
#define NPP 16            // nodes per partition (p = d >> 4)
#define QCAP 128          // per-node LDS queue capacity (Poisson(64) tail safe)
#define PCAP 12           // per-(block,partition) cell capacity (lambda=1.64)
#define MAX_NPART 640     // supports n_nodes <= 10240
#define OVF_PB 16         // per-block cell-overflow slots
#define LOCAL_OVF 64
#define THREADS 256
#define EPB (THREADS * 4)       // 1024 edges per bin slice
#define MAX_COOP_GRID 768       // 3 blocks/CU (42KB LDS) x 256 CU

typedef unsigned int u32;

__device__ __forceinline__ u32 f2bf(float f) {   // RNE fp32 -> bf16
    u32 x = __float_as_uint(f);
    return (x + 0x7FFFu + ((x >> 16) & 1u)) >> 16;
}
__device__ __forceinline__ float bf_lo(u32 u) { return __uint_as_float(u << 16); }
__device__ __forceinline__ float bf_hi(u32 u) { return __uint_as_float(u & 0xFFFF0000u); }

// MODE: 0 = bin only, 1 = gather only, 2 = fused cooperative (grid.sync).
// Entry encoding in a cell: bits[13:0]=src, bits[17:14]=dst&15; entry 0 also
// carries the cell count in bits[31:24]. Per-block overflow entries:
// (d<<14)|s written to povf[b*OVF_PB+*]; povf_cnt[b] written unconditionally
// -> NO global state needs pre-zeroing.
template <int MODE>
__global__ __launch_bounds__(THREADS) void graph_kernel(
        const int* __restrict__ src, const int* __restrict__ dst,
        const float* __restrict__ feat, u32* __restrict__ fbf,
        int* __restrict__ povf_cnt, int* __restrict__ povf,
        u32* __restrict__ bins, float* __restrict__ out,
        int n_edges, int n_nodes, int npart, int nblk, int npacks) {
    __shared__ u32 stage[MAX_NPART * PCAP];                     // 30 KB
    __shared__ int lcnt[MAX_NPART];                             // 2.5 KB
    __shared__ __attribute__((aligned(16))) int sq[NPP * QCAP]; // 8 KB
    __shared__ int scnt[NPP];
    __shared__ int sdeg[NPP];
    __shared__ int sovf[LOCAL_OVF];
    __shared__ int lovf[LOCAL_OVF];
    __shared__ int bovf_cnt, sovf_cnt, lovf_cnt;

    int tid = threadIdx.x;
    int b = blockIdx.x;

    if (MODE != 1) {
        // ---- fused feat -> packed bf16 ----
        for (int i = b * THREADS + tid; i < npacks; i += gridDim.x * THREADS) {
            float4 v = ((const float4*)feat)[i];
            u32 a = f2bf(v.x) | (f2bf(v.y) << 16);
            u32 c = f2bf(v.z) | (f2bf(v.w) << 16);
            ((uint2*)fbf)[i] = make_uint2(a, c);
        }
        if (b < nblk) {
            for (int i = tid; i < npart; i += THREADS) lcnt[i] = 0;
            if (tid == 0) bovf_cnt = 0;
            __syncthreads();

            int base = b * EPB + tid * 4;
            int s0 = 0, s1 = 0, s2 = 0, s3 = 0;
            int d0 = -1, d1 = -1, d2 = -1, d3 = -1;
            if (base + 3 < n_edges) {
                int4 sv = ((const int4*)src)[base >> 2];
                int4 dv = ((const int4*)dst)[base >> 2];
                s0 = sv.x; s1 = sv.y; s2 = sv.z; s3 = sv.w;
                d0 = dv.x; d1 = dv.y; d2 = dv.z; d3 = dv.w;
            } else if (base < n_edges) {
                if (base + 0 < n_edges) { s0 = src[base + 0]; d0 = dst[base + 0]; }
                if (base + 1 < n_edges) { s1 = src[base + 1]; d1 = dst[base + 1]; }
                if (base + 2 < n_edges) { s2 = src[base + 2]; d2 = dst[base + 2]; }
            }
            #define RANK(dK, sK)                                              \
                if (dK >= 0) {                                                \
                    int pK = dK >> 4;                                         \
                    int r = atomicAdd(&lcnt[pK], 1);                          \
                    if (r < PCAP) {                                           \
                        stage[pK * PCAP + r] =                                \
                            ((u32)(dK & 15) << 14) | (u32)sK;                 \
                    } else {                                                  \
                        int o = atomicAdd(&bovf_cnt, 1);                      \
                        if (o < OVF_PB)                                       \
                            povf[b * OVF_PB + o] = ((dK) << 14) | (sK);       \
                    }                                                         \
                }
            RANK(d0, s0)
            RANK(d1, s1)
            RANK(d2, s2)
            RANK(d3, s3)
            #undef RANK
            __syncthreads();

            // embed counts into entry 0 of each cell
            for (int p2 = tid; p2 < npart; p2 += THREADS) {
                int c = lcnt[p2]; if (c > PCAP) c = PCAP;
                stage[p2 * PCAP] = (stage[p2 * PCAP] & 0x3FFFFu) |
                                   ((u32)c << 24);
            }
            __syncthreads();

            // one contiguous 30KB streaming write per block
            uint4* d4 = (uint4*)(bins + (size_t)b * npart * PCAP);
            const uint4* s4 = (const uint4*)stage;
            int nv = npart * PCAP / 4;
            for (int i = tid; i < nv; i += THREADS) d4[i] = s4[i];
            if (tid == 0) {
                int c = bovf_cnt; if (c > OVF_PB) c = OVF_PB;
                povf_cnt[b] = c;
            }
        }
    }

    if constexpr (MODE == 2) {
        __threadfence();
        cg::this_grid().sync();
    }

    if (MODE != 0) {
        int p = b;
        if (p >= npart) return;
        int bstart = p * NPP;
        if (tid < NPP) { scnt[tid] = 0; sdeg[tid] = 0; }
        if (tid == 0) { sovf_cnt = 0; lovf_cnt = 0; }
        __syncthreads();

        #define PUSHE(eV) {                                                   \
            u32 e_ = (eV);                                                    \
            int s_ = (int)(e_ & 0x3FFFu);                                     \
            int dl_ = (int)((e_ >> 14) & 0xFu);                               \
            int pos_ = atomicAdd(&scnt[dl_], 1);                              \
            if (pos_ < QCAP) sq[dl_ * QCAP + pos_] = s_;                      \
            else { int o_ = atomicAdd(&lovf_cnt, 1);                          \
                   if (o_ < LOCAL_OVF) lovf[o_] = (int)(e_ & 0x3FFFFu); } }

        for (int q2 = tid; q2 < nblk; q2 += THREADS) {
            const uint4* cell4 =
                (const uint4*)(bins + ((size_t)q2 * npart + p) * PCAP);
            uint4 A = cell4[0];
            int c = (int)(A.x >> 24);
            if (c > 0) {
                PUSHE(A.x); if (c > 1) PUSHE(A.y);
                if (c > 2) PUSHE(A.z); if (c > 3) PUSHE(A.w);
                if (c > 4) {
                    uint4 B = cell4[1];
                    PUSHE(B.x); if (c > 5) PUSHE(B.y);
                    if (c > 6) PUSHE(B.z); if (c > 7) PUSHE(B.w);
                    if (c > 8) {
                        uint4 C = cell4[2];
                        PUSHE(C.x); if (c > 9) PUSHE(C.y);
                        if (c > 10) PUSHE(C.z); if (c > 11) PUSHE(C.w);
                    }
                }
            }
            int oc = povf_cnt[q2];
            if (oc < 0) oc = 0; if (oc > OVF_PB) oc = OVF_PB;
            for (int r = 0; r < oc; ++r) {
                int ent = povf[q2 * OVF_PB + r];
                int d = (ent >> 14) & 0x3FFF;
                if ((d >> 4) == p) {
                    atomicAdd(&sdeg[d & 15], 1);
                    int o = atomicAdd(&sovf_cnt, 1);
                    if (o < LOCAL_OVF) sovf[o] = ent;
                }
            }
        }
        #undef PUSHE
        __syncthreads();

        int g = tid >> 4;         // 16 groups, one node each
        int gl = tid & 15;
        const uint4* f4 = (const uint4*)fbf;   // row = 16 uint4 (128 bf16)
        int node = bstart + g;
        if (node < n_nodes) {
            int full = scnt[g] + sdeg[g];
            int degq = scnt[g] < QCAP ? scnt[g] : QCAP;
            const int* qq = &sq[g * QCAP];
            float a0 = 0.f, a1 = 0.f, a2 = 0.f, a3 = 0.f;
            float a4 = 0.f, a5 = 0.f, a6 = 0.f, a7 = 0.f;
            int i = 0;
            for (; i + 4 <= degq; i += 4) {
                int4 s4v = *(const int4*)&qq[i];  // uniform per group
                uint4 u0 = f4[(size_t)s4v.x * 16 + gl];
                uint4 u1 = f4[(size_t)s4v.y * 16 + gl];
                uint4 u2 = f4[(size_t)s4v.z * 16 + gl];
                uint4 u3 = f4[(size_t)s4v.w * 16 + gl];
                a0 += bf_lo(u0.x); a1 += bf_hi(u0.x); a2 += bf_lo(u0.y); a3 += bf_hi(u0.y);
                a4 += bf_lo(u0.z); a5 += bf_hi(u0.z); a6 += bf_lo(u0.w); a7 += bf_hi(u0.w);
                a0 += bf_lo(u1.x); a1 += bf_hi(u1.x); a2 += bf_lo(u1.y); a3 += bf_hi(u1.y);
                a4 += bf_lo(u1.z); a5 += bf_hi(u1.z); a6 += bf_lo(u1.w); a7 += bf_hi(u1.w);
                a0 += bf_lo(u2.x); a1 += bf_hi(u2.x); a2 += bf_lo(u2.y); a3 += bf_hi(u2.y);
                a4 += bf_lo(u2.z); a5 += bf_hi(u2.z); a6 += bf_lo(u2.w); a7 += bf_hi(u2.w);
                a0 += bf_lo(u3.x); a1 += bf_hi(u3.x); a2 += bf_lo(u3.y); a3 += bf_hi(u3.y);
                a4 += bf_lo(u3.z); a5 += bf_hi(u3.z); a6 += bf_lo(u3.w); a7 += bf_hi(u3.w);
            }
            for (; i < degq; ++i) {
                uint4 u = f4[(size_t)qq[i] * 16 + gl];
                a0 += bf_lo(u.x); a1 += bf_hi(u.x); a2 += bf_lo(u.y); a3 += bf_hi(u.y);
                a4 += bf_lo(u.z); a5 += bf_hi(u.z); a6 += bf_lo(u.w); a7 += bf_hi(u.w);
            }
            float sc = rsqrtf((float)(full > 1 ? full : 1));
            float4 r0 = { a0 * sc, a1 * sc, a2 * sc, a3 * sc };
            float4 r1 = { a4 * sc, a5 * sc, a6 * sc, a7 * sc };
            ((float4*)out)[(size_t)node * 32 + gl * 2 + 0] = r0;
            ((float4*)out)[(size_t)node * 32 + gl * 2 + 1] = r1;
        }
        __syncthreads();

        // queue-overflow patch (expected 0 entries)
        int lc = lovf_cnt; if (lc > LOCAL_OVF) lc = LOCAL_OVF;
        for (int k = g; k < lc; k += NPP) {
            int ent = lovf[k];
            int dl = (ent >> 14) & 15;
            int s = ent & 0x3FFF;
            int full = scnt[dl] + sdeg[dl];
            float sc = rsqrtf((float)(full > 1 ? full : 1));
            uint4 u = f4[(size_t)s * 16 + gl];
            float* orow = out + (size_t)(bstart + dl) * D_FEAT + gl * 8;
            atomicAdd(&orow[0], bf_lo(u.x) * sc);
            atomicAdd(&orow[1], bf_hi(u.x) * sc);
            atomicAdd(&orow[2], bf_lo(u.y) * sc);
            atomicAdd(&orow[3], bf_hi(u.y) * sc);
            atomicAdd(&orow[4], bf_lo(u.z) * sc);
            atomicAdd(&orow[5], bf_hi(u.z) * sc);
            atomicAdd(&orow[6], bf_lo(u.w) * sc);
            atomicAdd(&orow[7], bf_hi(u.w) * sc);
        }
        // cell-overflow patch (expected 0 entries)
        int oc2 = sovf_cnt; if (oc2 > LOCAL_OVF) oc2 = LOCAL_OVF;
        for (int k = g; k < oc2; k += NPP) {
            int ent = sovf[k];
            int dl = (ent >> 14) & 15;
            int s = ent & 0x3FFF;
            int full = scnt[dl] + sdeg[dl];
            float sc = rsqrtf((float)(full > 1 ? full : 1));
            uint4 u = f4[(size_t)s * 16 + gl];
            float* orow = out + (size_t)(bstart + dl) * D_FEAT + gl * 8;
            atomicAdd(&orow[0], bf_lo(u.x) * sc);
            atomicAdd(&orow[1], bf_hi(u.x) * sc);
            atomicAdd(&orow[2], bf_lo(u.y) * sc);
            atomicAdd(&orow[3], bf_hi(u.y) * sc);
            atomicAdd(&orow[4], bf_lo(u.z) * sc);
            atomicAdd(&orow[5], bf_hi(u.z) * sc);
            atomicAdd(&orow[6], bf_lo(u.w) * sc);
            atomicAdd(&orow[7], bf_hi(u.w) * sc);
        }
    }
}

// ---------------- fallback path (fp32 atomics) ----------------

__global__ void zero_kernel(float* __restrict__ out, float* __restrict__ deg,
                            int n_out, int n_deg) {
    int i = blockIdx.x * blockDim.x + threadIdx.x;
    if (i < n_out) out[i] = 0.0f;
    if (i < n_deg) deg[i] = 0.0f;
}

__global__ void scatter_kernel(const float* __restrict__ feat,
                               const int* __restrict__ src,
                               const int* __restrict__ dst,
                               float* __restrict__ out,
                               float* __restrict__ deg,
                               int n_edges) {
    long long gid = (long long)blockIdx.x * blockDim.x + threadIdx.x;
    int e = (int)(gid >> 7);
    int f = (int)(gid & 127);
    if (e >= n_edges) return;
    int s = src[e];
    int d = dst[e];
    float v = feat[(long long)s * D_FEAT + f];
    atomicAdd(&out[(long long)d * D_FEAT + f], v);
    if (f == 0) atomicAdd(&deg[d], 1.0f);
}

__global__ void norm_kernel(float* __restrict__ out, const float* __restrict__ deg,
                            int n_out) {
    int gid = blockIdx.x * blockDim.x + threadIdx.x;
    if (gid >= n_out) return;
    int i = gid >> 7;
    float dg = fmaxf(deg[i], 1.0f);
    out[gid] = out[gid] * rsqrtf(dg);
}

extern "C" void kernel_launch(void* const* d_in, const int* in_sizes, int n_in,
                              void* d_out, int out_size, void* d_ws, size_t ws_size,
                              hipStream_t stream) {
    const float* feat = (const float*)d_in[0];
    const int*   src  = (const int*)d_in[1];
    const int*   dst  = (const int*)d_in[2];
    float* out = (float*)d_out;

    const int n_edges = in_sizes[1];
    const int n_out   = out_size;            // n_nodes * 128
    const int n_nodes = n_out / D_FEAT;

    int npart  = (n_nodes + NPP - 1) / NPP;
    int nblk   = (n_edges + EPB - 1) / EPB;
    int npacks = n_out / 4;

    // ws (ints): povf_cnt[nblk] | povf[nblk*OVF_PB] | pad | bins[nblk*npart*PCAP]
    //            | fbf[n_out/2]
    size_t head = ((size_t)nblk + (size_t)nblk * OVF_PB + 3) & ~(size_t)3;
    size_t bins_ints = (size_t)nblk * npart * PCAP;
    size_t fbf_off = (head + bins_ints + 3) & ~(size_t)3;
    size_t need = (fbf_off + (size_t)n_out / 2) * sizeof(int);

    if (ws_size >= need && npart <= MAX_NPART && n_nodes <= 16384) {
        int* povf_cnt = (int*)d_ws;
        int* povf     = povf_cnt + nblk;
        u32* bins     = (u32*)d_ws + head;
        u32* fbf      = (u32*)d_ws + fbf_off;

        int grid = nblk > npart ? nblk : npart;
        if (grid <= MAX_COOP_GRID) {
            // mutable locals for kernelParams
            const int* a_src = src; const int* a_dst = dst;
            const float* a_feat = feat; u32* a_fbf = fbf;
            int* a_pc = povf_cnt; int* a_po = povf;
            u32* a_bins = bins; float* a_out = out;
            int a_ne = n_edges, a_nn = n_nodes, a_np = npart,
                a_nb = nblk, a_npk = npacks;
            void* ka[] = { (void*)&a_src, (void*)&a_dst, (void*)&a_feat,
                           (void*)&a_fbf, (void*)&a_pc, (void*)&a_po,
                           (void*)&a_bins, (void*)&a_out, (void*)&a_ne,
                           (void*)&a_nn, (void*)&a_np, (void*)&a_nb,
                           (void*)&a_npk };
            hipError_t e = hipLaunchCooperativeKernel(
                (const void*)graph_kernel<2>, dim3(grid), dim3(THREADS),
                ka, 0, stream);
            if (e == hipSuccess) return;
        }
        // non-cooperative fallback: same phases as two dispatches
        graph_kernel<0><<<nblk, THREADS, 0, stream>>>(
            src, dst, feat, fbf, povf_cnt, povf, bins, out,
            n_edges, n_nodes, npart, nblk, npacks);
        graph_kernel<1><<<npart, THREADS, 0, stream>>>(
            src, dst, feat, fbf, povf_cnt, povf, bins, out,
            n_edges, n_nodes, npart, nblk, npacks);
    } else {
        float* deg = (float*)d_ws;
        {
            int threads = 256;
            int blocks = (n_out + threads - 1) / threads;
            zero_kernel<<<blocks, threads, 0, stream>>>(out, deg, n_out, n_nodes);
        }
        {
            long long total = (long long)n_edges * D_FEAT;
            int threads = 256;
            int blocks = (int)((total + threads - 1) / threads);
            scatter_kernel<<<blocks, threads, 0, stream>>>(feat, src, dst, out, deg, n_edges);
        }
        {
            int threads = 256;
            int blocks = (n_out + threads - 1) / threads;
            norm_kernel<<<blocks, threads, 0, stream>>>(out, deg, n_out);
        }
    }
}

// Round 12
// 32.246 us; speedup vs baseline: 5.9101x; 5.9101x over previous
//
#include <hip/hip_runtime.h>

#define D_FEAT 128
#define NPP 16            // nodes per partition (p = d >> 4)
#define QCAP 128          // per-node LDS queue capacity (Poisson(64) tail safe)
#define PCAP 12           // per-(block,partition) cell capacity (lambda=3.3)
#define MAX_NPART 640     // supports n_nodes <= 10240
#define OVF_PB 32         // per-block cell-overflow slots
#define LOCAL_OVF 64
#define BIN_THREADS 512
#define EPB (BIN_THREADS * 4)     // 2048 edges per bin block

typedef unsigned int u32;

__device__ __forceinline__ u32 f2bf(float f) {   // RNE fp32 -> bf16
    u32 x = __float_as_uint(f);
    return (x + 0x7FFFu + ((x >> 16) & 1u)) >> 16;
}
__device__ __forceinline__ float bf_lo(u32 u) { return __uint_as_float(u << 16); }
__device__ __forceinline__ float bf_hi(u32 u) { return __uint_as_float(u & 0xFFFF0000u); }

// ---------------- Kernel 1: feat->bf16 + cursor-free binning ----------------
// Cell (p, q) at bins[(q*npart+p)*PCAP] holds <=PCAP entries; entry encoding
// bits[13:0]=src, bits[17:14]=dst&15; entry 0 carries cell count in bits
// [28:24]. Per-block overflow -> povf[b*OVF_PB..], povf_cnt[b] written
// UNCONDITIONALLY -> no global state needs pre-zeroing, no memset dispatch.
__global__ __launch_bounds__(BIN_THREADS) void bin_kernel(
        const int* __restrict__ src, const int* __restrict__ dst,
        const float* __restrict__ feat, u32* __restrict__ fbf,
        int* __restrict__ povf_cnt, int* __restrict__ povf,
        u32* __restrict__ bins,
        int n_edges, int npart, int nblk, int npacks) {
    __shared__ u32 stage[MAX_NPART * PCAP];   // 30 KB
    __shared__ int lcnt[MAX_NPART];           // 2.5 KB
    __shared__ int bovf_cnt;
    int tid = threadIdx.x;
    int b = blockIdx.x;

    // fused feat -> packed bf16 (grid-stride)
    for (int i = b * BIN_THREADS + tid; i < npacks;
         i += gridDim.x * BIN_THREADS) {
        float4 v = ((const float4*)feat)[i];
        u32 a = f2bf(v.x) | (f2bf(v.y) << 16);
        u32 c = f2bf(v.z) | (f2bf(v.w) << 16);
        ((uint2*)fbf)[i] = make_uint2(a, c);
    }

    for (int i = tid; i < npart; i += BIN_THREADS) lcnt[i] = 0;
    if (tid == 0) bovf_cnt = 0;
    __syncthreads();

    int base = b * EPB + tid * 4;
    int s0 = 0, s1 = 0, s2 = 0, s3 = 0, d0 = -1, d1 = -1, d2 = -1, d3 = -1;
    if (base + 3 < n_edges) {
        int4 sv = ((const int4*)src)[base >> 2];
        int4 dv = ((const int4*)dst)[base >> 2];
        s0 = sv.x; s1 = sv.y; s2 = sv.z; s3 = sv.w;
        d0 = dv.x; d1 = dv.y; d2 = dv.z; d3 = dv.w;
    } else if (base < n_edges) {
        if (base + 0 < n_edges) { s0 = src[base + 0]; d0 = dst[base + 0]; }
        if (base + 1 < n_edges) { s1 = src[base + 1]; d1 = dst[base + 1]; }
        if (base + 2 < n_edges) { s2 = src[base + 2]; d2 = dst[base + 2]; }
    }
    #define RANK(dK, sK)                                                      \
        if (dK >= 0) {                                                        \
            int pK = dK >> 4;                                                 \
            int r = atomicAdd(&lcnt[pK], 1);                                  \
            if (r < PCAP) {                                                   \
                stage[pK * PCAP + r] = ((u32)(dK & 15) << 14) | (u32)sK;      \
            } else {                                                          \
                int o = atomicAdd(&bovf_cnt, 1);                              \
                if (o < OVF_PB)                                               \
                    povf[b * OVF_PB + o] = ((dK) << 14) | (sK);               \
            }                                                                 \
        }
    RANK(d0, s0)
    RANK(d1, s1)
    RANK(d2, s2)
    RANK(d3, s3)
    #undef RANK
    __syncthreads();

    // embed counts into entry 0 of each cell
    for (int p2 = tid; p2 < npart; p2 += BIN_THREADS) {
        int c = lcnt[p2]; if (c > PCAP) c = PCAP;
        stage[p2 * PCAP] = (stage[p2 * PCAP] & 0x3FFFFu) | ((u32)c << 24);
    }
    __syncthreads();

    // one contiguous 30KB streaming write per block
    uint4* dd4 = (uint4*)(bins + (size_t)b * npart * PCAP);
    const uint4* ss4 = (const uint4*)stage;
    int nv = npart * PCAP / 4;
    for (int i = tid; i < nv; i += BIN_THREADS) dd4[i] = ss4[i];
    if (tid == 0) {
        int c = bovf_cnt; if (c > OVF_PB) c = OVF_PB;
        povf_cnt[b] = c;    // unconditional -> no pre-zero needed
    }
}

// ---------------- Kernel 2: queue build + bf16 gather + folded patch --------
// Block p: read own cells (uint4, count-guarded), bin into 16 per-node LDS
// queues, 16-lane-group uint4 gather, normalize, write once; overflow edges
// (bin-cell + queue) handled exactly via atomics afterwards (expected 0).
__global__ __launch_bounds__(256) void gather_kernel(
        const u32* __restrict__ fbf, const u32* __restrict__ bins,
        const int* __restrict__ povf_cnt, const int* __restrict__ povf,
        float* __restrict__ out, int n_nodes, int npart, int nblk) {
    __shared__ __attribute__((aligned(16))) int sq[NPP * QCAP];   // 8 KB
    __shared__ int scnt[NPP];
    __shared__ int sdeg[NPP];
    __shared__ int sovf[LOCAL_OVF];
    __shared__ int lovf[LOCAL_OVF];
    __shared__ int sovf_cnt, lovf_cnt;
    int tid = threadIdx.x;
    int p = blockIdx.x;
    int bstart = p * NPP;
    if (tid < NPP) { scnt[tid] = 0; sdeg[tid] = 0; }
    if (tid == 0) { sovf_cnt = 0; lovf_cnt = 0; }
    __syncthreads();

    #define PUSHE(eV) {                                                       \
        u32 e_ = (eV);                                                        \
        int s_ = (int)(e_ & 0x3FFFu);                                         \
        int dl_ = (int)((e_ >> 14) & 0xFu);                                   \
        int pos_ = atomicAdd(&scnt[dl_], 1);                                  \
        if (pos_ < QCAP) sq[dl_ * QCAP + pos_] = s_;                          \
        else { int o_ = atomicAdd(&lovf_cnt, 1);                              \
               if (o_ < LOCAL_OVF) lovf[o_] = (int)(e_ & 0x3FFFFu); } }

    for (int q2 = tid; q2 < nblk; q2 += 256) {
        const uint4* cell4 = (const uint4*)(bins + ((size_t)q2 * npart + p) * PCAP);
        uint4 A = cell4[0];
        int c = (int)(A.x >> 24);
        if (c > 0) {
            PUSHE(A.x); if (c > 1) PUSHE(A.y);
            if (c > 2) PUSHE(A.z); if (c > 3) PUSHE(A.w);
            if (c > 4) {
                uint4 B = cell4[1];
                PUSHE(B.x); if (c > 5) PUSHE(B.y);
                if (c > 6) PUSHE(B.z); if (c > 7) PUSHE(B.w);
                if (c > 8) {
                    uint4 C = cell4[2];
                    PUSHE(C.x); if (c > 9) PUSHE(C.y);
                    if (c > 10) PUSHE(C.z); if (c > 11) PUSHE(C.w);
                }
            }
        }
        int oc = povf_cnt[q2];
        if (oc < 0) oc = 0; if (oc > OVF_PB) oc = OVF_PB;
        for (int r = 0; r < oc; ++r) {
            int ent = povf[q2 * OVF_PB + r];
            int d = (ent >> 14) & 0x3FFF;
            if ((d >> 4) == p) {
                atomicAdd(&sdeg[d & 15], 1);
                int o = atomicAdd(&sovf_cnt, 1);
                if (o < LOCAL_OVF) sovf[o] = ent;
            }
        }
    }
    #undef PUSHE
    __syncthreads();

    int g  = tid >> 4;        // 16 groups, one node each
    int gl = tid & 15;
    const uint4* f4 = (const uint4*)fbf;   // row = 16 uint4 (128 bf16)
    int node = bstart + g;
    if (node < n_nodes) {
        int full = scnt[g] + sdeg[g];
        int degq = scnt[g] < QCAP ? scnt[g] : QCAP;
        const int* qq = &sq[g * QCAP];
        float a0 = 0.f, a1 = 0.f, a2 = 0.f, a3 = 0.f;
        float a4 = 0.f, a5 = 0.f, a6 = 0.f, a7 = 0.f;
        int i = 0;
        for (; i + 4 <= degq; i += 4) {
            int4 s4 = *(const int4*)&qq[i];   // uniform per group -> broadcast
            uint4 u0 = f4[(size_t)s4.x * 16 + gl];
            uint4 u1 = f4[(size_t)s4.y * 16 + gl];
            uint4 u2 = f4[(size_t)s4.z * 16 + gl];
            uint4 u3 = f4[(size_t)s4.w * 16 + gl];
            a0 += bf_lo(u0.x); a1 += bf_hi(u0.x); a2 += bf_lo(u0.y); a3 += bf_hi(u0.y);
            a4 += bf_lo(u0.z); a5 += bf_hi(u0.z); a6 += bf_lo(u0.w); a7 += bf_hi(u0.w);
            a0 += bf_lo(u1.x); a1 += bf_hi(u1.x); a2 += bf_lo(u1.y); a3 += bf_hi(u1.y);
            a4 += bf_lo(u1.z); a5 += bf_hi(u1.z); a6 += bf_lo(u1.w); a7 += bf_hi(u1.w);
            a0 += bf_lo(u2.x); a1 += bf_hi(u2.x); a2 += bf_lo(u2.y); a3 += bf_hi(u2.y);
            a4 += bf_lo(u2.z); a5 += bf_hi(u2.z); a6 += bf_lo(u2.w); a7 += bf_hi(u2.w);
            a0 += bf_lo(u3.x); a1 += bf_hi(u3.x); a2 += bf_lo(u3.y); a3 += bf_hi(u3.y);
            a4 += bf_lo(u3.z); a5 += bf_hi(u3.z); a6 += bf_lo(u3.w); a7 += bf_hi(u3.w);
        }
        for (; i < degq; ++i) {
            uint4 u = f4[(size_t)qq[i] * 16 + gl];
            a0 += bf_lo(u.x); a1 += bf_hi(u.x); a2 += bf_lo(u.y); a3 += bf_hi(u.y);
            a4 += bf_lo(u.z); a5 += bf_hi(u.z); a6 += bf_lo(u.w); a7 += bf_hi(u.w);
        }
        float sc = rsqrtf((float)(full > 1 ? full : 1));
        float4 r0 = { a0 * sc, a1 * sc, a2 * sc, a3 * sc };
        float4 r1 = { a4 * sc, a5 * sc, a6 * sc, a7 * sc };
        ((float4*)out)[(size_t)node * 32 + gl * 2 + 0] = r0;
        ((float4*)out)[(size_t)node * 32 + gl * 2 + 1] = r1;
    }
    __syncthreads();

    // queue-overflow patch (expected 0 entries)
    int lc = lovf_cnt; if (lc > LOCAL_OVF) lc = LOCAL_OVF;
    for (int k = g; k < lc; k += NPP) {
        int ent = lovf[k];
        int dl = (ent >> 14) & 15;
        int s = ent & 0x3FFF;
        int full = scnt[dl] + sdeg[dl];
        float sc = rsqrtf((float)(full > 1 ? full : 1));
        uint4 u = f4[(size_t)s * 16 + gl];
        float* orow = out + (size_t)(bstart + dl) * D_FEAT + gl * 8;
        atomicAdd(&orow[0], bf_lo(u.x) * sc);
        atomicAdd(&orow[1], bf_hi(u.x) * sc);
        atomicAdd(&orow[2], bf_lo(u.y) * sc);
        atomicAdd(&orow[3], bf_hi(u.y) * sc);
        atomicAdd(&orow[4], bf_lo(u.z) * sc);
        atomicAdd(&orow[5], bf_hi(u.z) * sc);
        atomicAdd(&orow[6], bf_lo(u.w) * sc);
        atomicAdd(&orow[7], bf_hi(u.w) * sc);
    }
    // bin-cell overflow patch (expected 0 entries)
    int oc2 = sovf_cnt; if (oc2 > LOCAL_OVF) oc2 = LOCAL_OVF;
    for (int k = g; k < oc2; k += NPP) {
        int ent = sovf[k];
        int dl = (ent >> 14) & 15;
        int s = ent & 0x3FFF;
        int full = scnt[dl] + sdeg[dl];
        float sc = rsqrtf((float)(full > 1 ? full : 1));
        uint4 u = f4[(size_t)s * 16 + gl];
        float* orow = out + (size_t)(bstart + dl) * D_FEAT + gl * 8;
        atomicAdd(&orow[0], bf_lo(u.x) * sc);
        atomicAdd(&orow[1], bf_hi(u.x) * sc);
        atomicAdd(&orow[2], bf_lo(u.y) * sc);
        atomicAdd(&orow[3], bf_hi(u.y) * sc);
        atomicAdd(&orow[4], bf_lo(u.z) * sc);
        atomicAdd(&orow[5], bf_hi(u.z) * sc);
        atomicAdd(&orow[6], bf_lo(u.w) * sc);
        atomicAdd(&orow[7], bf_hi(u.w) * sc);
    }
}

// ---------------- fallback path (fp32 atomics) ----------------

__global__ void zero_kernel(float* __restrict__ out, float* __restrict__ deg,
                            int n_out, int n_deg) {
    int i = blockIdx.x * blockDim.x + threadIdx.x;
    if (i < n_out) out[i] = 0.0f;
    if (i < n_deg) deg[i] = 0.0f;
}

__global__ void scatter_kernel(const float* __restrict__ feat,
                               const int* __restrict__ src,
                               const int* __restrict__ dst,
                               float* __restrict__ out,
                               float* __restrict__ deg,
                               int n_edges) {
    long long gid = (long long)blockIdx.x * blockDim.x + threadIdx.x;
    int e = (int)(gid >> 7);
    int f = (int)(gid & 127);
    if (e >= n_edges) return;
    int s = src[e];
    int d = dst[e];
    float v = feat[(long long)s * D_FEAT + f];
    atomicAdd(&out[(long long)d * D_FEAT + f], v);
    if (f == 0) atomicAdd(&deg[d], 1.0f);
}

__global__ void norm_kernel(float* __restrict__ out, const float* __restrict__ deg,
                            int n_out) {
    int gid = blockIdx.x * blockDim.x + threadIdx.x;
    if (gid >= n_out) return;
    int i = gid >> 7;
    float dg = fmaxf(deg[i], 1.0f);
    out[gid] = out[gid] * rsqrtf(dg);
}

extern "C" void kernel_launch(void* const* d_in, const int* in_sizes, int n_in,
                              void* d_out, int out_size, void* d_ws, size_t ws_size,
                              hipStream_t stream) {
    const float* feat = (const float*)d_in[0];
    const int*   src  = (const int*)d_in[1];
    const int*   dst  = (const int*)d_in[2];
    float* out = (float*)d_out;

    const int n_edges = in_sizes[1];
    const int n_out   = out_size;            // n_nodes * 128
    const int n_nodes = n_out / D_FEAT;

    int npart  = (n_nodes + NPP - 1) / NPP;
    int nblk   = (n_edges + EPB - 1) / EPB;
    int npacks = n_out / 4;

    // ws (ints): povf_cnt[nblk] | povf[nblk*OVF_PB] | pad | bins[nblk*npart*PCAP]
    //            | fbf[n_out/2]
    size_t head = ((size_t)nblk + (size_t)nblk * OVF_PB + 3) & ~(size_t)3;
    size_t bins_ints = (size_t)nblk * npart * PCAP;
    size_t fbf_off = (head + bins_ints + 3) & ~(size_t)3;
    size_t need = (fbf_off + (size_t)n_out / 2) * sizeof(int);

    if (ws_size >= need && npart <= MAX_NPART && n_nodes <= 16384) {
        int* povf_cnt = (int*)d_ws;
        int* povf     = povf_cnt + nblk;
        u32* bins     = (u32*)d_ws + head;
        u32* fbf      = (u32*)d_ws + fbf_off;

        bin_kernel<<<nblk, BIN_THREADS, 0, stream>>>(
            src, dst, feat, fbf, povf_cnt, povf, bins,
            n_edges, npart, nblk, npacks);
        gather_kernel<<<npart, 256, 0, stream>>>(
            fbf, bins, povf_cnt, povf, out, n_nodes, npart, nblk);
    } else {
        float* deg = (float*)d_ws;
        {
            int threads = 256;
            int blocks = (n_out + threads - 1) / threads;
            zero_kernel<<<blocks, threads, 0, stream>>>(out, deg, n_out, n_nodes);
        }
        {
            long long total = (long long)n_edges * D_FEAT;
            int threads = 256;
            int blocks = (int)((total + threads - 1) / threads);
            scatter_kernel<<<blocks, threads, 0, stream>>>(feat, src, dst, out, deg, n_edges);
        }
        {
            int threads = 256;
            int blocks = (n_out + threads - 1) / threads;
            norm_kernel<<<blocks, threads, 0, stream>>>(out, deg, n_out);
        }
    }
}

// Round 13
// 31.826 us; speedup vs baseline: 5.9880x; 1.0132x over previous
//
#include <hip/hip_runtime.h>

#define D_FEAT 128
#define NPP 16            // nodes per partition (p = d >> 4)
#define QCAP 128          // per-node LDS queue capacity (Poisson(64) tail safe)
#define PCAP 16           // per-(block,partition) cell capacity (lambda=6.55)
#define SSTRIDE 17        // stage stride (bank-conflict padding)
#define MAX_NPART 640     // supports n_nodes <= 10240
#define OVF_PB 64         // per-block cell-overflow slots
#define LOCAL_OVF 64
#define BIN_THREADS 1024
#define EPB (BIN_THREADS * 4)     // 4096 edges per bin block

typedef unsigned int u32;

__device__ __forceinline__ u32 f2bf(float f) {   // RNE fp32 -> bf16
    u32 x = __float_as_uint(f);
    return (x + 0x7FFFu + ((x >> 16) & 1u)) >> 16;
}
__device__ __forceinline__ float bf_lo(u32 u) { return __uint_as_float(u << 16); }
__device__ __forceinline__ float bf_hi(u32 u) { return __uint_as_float(u & 0xFFFF0000u); }

// ---------------- Kernel 1: feat->bf16 + cursor-free binning ----------------
// Cell (p, q) at bins[(q*npart+p)*PCAP]: <=PCAP entries, entry = bits[13:0]=src,
// bits[17:14]=dst&15; entry 0 carries count in bits[28:24]. Per-block overflow
// -> povf, povf_cnt written UNCONDITIONALLY (no pre-zeroing anywhere).
__global__ __launch_bounds__(BIN_THREADS) void bin_kernel(
        const int* __restrict__ src, const int* __restrict__ dst,
        const float* __restrict__ feat, u32* __restrict__ fbf,
        int* __restrict__ povf_cnt, int* __restrict__ povf,
        u32* __restrict__ bins,
        int n_edges, int npart, int nblk, int npacks) {
    __shared__ u32 stage[MAX_NPART * SSTRIDE];   // 43.5 KB (stride-17 padded)
    __shared__ int lcnt[MAX_NPART];              // 2.5 KB
    __shared__ int bovf_cnt;
    int tid = threadIdx.x;
    int b = blockIdx.x;

    // fused feat -> packed bf16 (grid-stride)
    for (int i = b * BIN_THREADS + tid; i < npacks;
         i += gridDim.x * BIN_THREADS) {
        float4 v = ((const float4*)feat)[i];
        u32 a = f2bf(v.x) | (f2bf(v.y) << 16);
        u32 c = f2bf(v.z) | (f2bf(v.w) << 16);
        ((uint2*)fbf)[i] = make_uint2(a, c);
    }

    for (int i = tid; i < npart; i += BIN_THREADS) lcnt[i] = 0;
    if (tid == 0) bovf_cnt = 0;
    __syncthreads();

    int base = b * EPB + tid * 4;
    int s0 = 0, s1 = 0, s2 = 0, s3 = 0, d0 = -1, d1 = -1, d2 = -1, d3 = -1;
    if (base + 3 < n_edges) {
        int4 sv = ((const int4*)src)[base >> 2];
        int4 dv = ((const int4*)dst)[base >> 2];
        s0 = sv.x; s1 = sv.y; s2 = sv.z; s3 = sv.w;
        d0 = dv.x; d1 = dv.y; d2 = dv.z; d3 = dv.w;
    } else if (base < n_edges) {
        if (base + 0 < n_edges) { s0 = src[base + 0]; d0 = dst[base + 0]; }
        if (base + 1 < n_edges) { s1 = src[base + 1]; d1 = dst[base + 1]; }
        if (base + 2 < n_edges) { s2 = src[base + 2]; d2 = dst[base + 2]; }
    }
    #define RANK(dK, sK)                                                      \
        if (dK >= 0) {                                                        \
            int pK = dK >> 4;                                                 \
            int r = atomicAdd(&lcnt[pK], 1);                                  \
            if (r < PCAP) {                                                   \
                stage[pK * SSTRIDE + r] = ((u32)(dK & 15) << 14) | (u32)sK;   \
            } else {                                                          \
                int o = atomicAdd(&bovf_cnt, 1);                              \
                if (o < OVF_PB)                                               \
                    povf[b * OVF_PB + o] = ((dK) << 14) | (sK);               \
            }                                                                 \
        }
    RANK(d0, s0)
    RANK(d1, s1)
    RANK(d2, s2)
    RANK(d3, s3)
    #undef RANK
    __syncthreads();

    // embed counts into entry 0 of each cell
    for (int p2 = tid; p2 < npart; p2 += BIN_THREADS) {
        int c = lcnt[p2]; if (c > PCAP) c = PCAP;
        stage[p2 * SSTRIDE] = (stage[p2 * SSTRIDE] & 0x3FFFFu) |
                              ((u32)c << 24);
    }
    __syncthreads();

    // stream out: word i -> cell p=i>>4, rank r=i&15 (LDS reads ~stride-1)
    u32* bout = bins + (size_t)b * npart * PCAP;
    int nw = npart * PCAP;
    for (int i = tid; i < nw; i += BIN_THREADS)
        bout[i] = stage[(i >> 4) * SSTRIDE + (i & 15)];
    if (tid == 0) {
        int c = bovf_cnt; if (c > OVF_PB) c = OVF_PB;
        povf_cnt[b] = c;    // unconditional -> no pre-zero needed
    }
}

// ---------------- Kernel 2: queue build + bf16 gather + folded patch --------
__global__ __launch_bounds__(256) void gather_kernel(
        const u32* __restrict__ fbf, const u32* __restrict__ bins,
        const int* __restrict__ povf_cnt, const int* __restrict__ povf,
        float* __restrict__ out, int n_nodes, int npart, int nblk) {
    __shared__ __attribute__((aligned(16))) int sq[NPP * QCAP];   // 8 KB
    __shared__ int scnt[NPP];
    __shared__ int sdeg[NPP];
    __shared__ int sovf[LOCAL_OVF];
    __shared__ int lovf[LOCAL_OVF];
    __shared__ int sovf_cnt, lovf_cnt;
    int tid = threadIdx.x;
    int p = blockIdx.x;
    int bstart = p * NPP;
    if (tid < NPP) { scnt[tid] = 0; sdeg[tid] = 0; }
    if (tid == 0) { sovf_cnt = 0; lovf_cnt = 0; }
    __syncthreads();

    #define PUSHE(eV) {                                                       \
        u32 e_ = (eV);                                                        \
        int s_ = (int)(e_ & 0x3FFFu);                                         \
        int dl_ = (int)((e_ >> 14) & 0xFu);                                   \
        int pos_ = atomicAdd(&scnt[dl_], 1);                                  \
        if (pos_ < QCAP) sq[dl_ * QCAP + pos_] = s_;                          \
        else { int o_ = atomicAdd(&lovf_cnt, 1);                              \
               if (o_ < LOCAL_OVF) lovf[o_] = (int)(e_ & 0x3FFFFu); } }

    for (int q2 = tid; q2 < nblk; q2 += 256) {
        const uint4* cell4 = (const uint4*)(bins + ((size_t)q2 * npart + p) * PCAP);
        uint4 A = cell4[0];
        int c = (int)(A.x >> 24);
        if (c > 0) {
            PUSHE(A.x); if (c > 1) PUSHE(A.y);
            if (c > 2) PUSHE(A.z); if (c > 3) PUSHE(A.w);
            if (c > 4) {
                uint4 B = cell4[1];
                PUSHE(B.x); if (c > 5) PUSHE(B.y);
                if (c > 6) PUSHE(B.z); if (c > 7) PUSHE(B.w);
                if (c > 8) {
                    uint4 C = cell4[2];
                    PUSHE(C.x); if (c > 9) PUSHE(C.y);
                    if (c > 10) PUSHE(C.z); if (c > 11) PUSHE(C.w);
                    if (c > 12) {
                        uint4 D = cell4[3];
                        PUSHE(D.x); if (c > 13) PUSHE(D.y);
                        if (c > 14) PUSHE(D.z); if (c > 15) PUSHE(D.w);
                    }
                }
            }
        }
        int oc = povf_cnt[q2];
        if (oc < 0) oc = 0; if (oc > OVF_PB) oc = OVF_PB;
        for (int r = 0; r < oc; ++r) {
            int ent = povf[q2 * OVF_PB + r];
            int d = (ent >> 14) & 0x3FFF;
            if ((d >> 4) == p) {
                atomicAdd(&sdeg[d & 15], 1);
                int o = atomicAdd(&sovf_cnt, 1);
                if (o < LOCAL_OVF) sovf[o] = ent;
            }
        }
    }
    #undef PUSHE
    __syncthreads();

    int g  = tid >> 4;        // 16 groups, one node each
    int gl = tid & 15;
    const uint4* f4 = (const uint4*)fbf;   // row = 16 uint4 (128 bf16)
    int node = bstart + g;
    if (node < n_nodes) {
        int full = scnt[g] + sdeg[g];
        int degq = scnt[g] < QCAP ? scnt[g] : QCAP;
        const int* qq = &sq[g * QCAP];
        float a0 = 0.f, a1 = 0.f, a2 = 0.f, a3 = 0.f;
        float a4 = 0.f, a5 = 0.f, a6 = 0.f, a7 = 0.f;
        int i = 0;
        #define ACC(U)                                                        \
            a0 += bf_lo(U.x); a1 += bf_hi(U.x); a2 += bf_lo(U.y);             \
            a3 += bf_hi(U.y); a4 += bf_lo(U.z); a5 += bf_hi(U.z);             \
            a6 += bf_lo(U.w); a7 += bf_hi(U.w);
        for (; i + 8 <= degq; i += 8) {       // 8 independent row loads
            int4 sA = *(const int4*)&qq[i];
            int4 sB = *(const int4*)&qq[i + 4];
            uint4 u0 = f4[(size_t)sA.x * 16 + gl];
            uint4 u1 = f4[(size_t)sA.y * 16 + gl];
            uint4 u2 = f4[(size_t)sA.z * 16 + gl];
            uint4 u3 = f4[(size_t)sA.w * 16 + gl];
            uint4 u4 = f4[(size_t)sB.x * 16 + gl];
            uint4 u5 = f4[(size_t)sB.y * 16 + gl];
            uint4 u6 = f4[(size_t)sB.z * 16 + gl];
            uint4 u7 = f4[(size_t)sB.w * 16 + gl];
            ACC(u0) ACC(u1) ACC(u2) ACC(u3) ACC(u4) ACC(u5) ACC(u6) ACC(u7)
        }
        for (; i + 4 <= degq; i += 4) {
            int4 sA = *(const int4*)&qq[i];
            uint4 u0 = f4[(size_t)sA.x * 16 + gl];
            uint4 u1 = f4[(size_t)sA.y * 16 + gl];
            uint4 u2 = f4[(size_t)sA.z * 16 + gl];
            uint4 u3 = f4[(size_t)sA.w * 16 + gl];
            ACC(u0) ACC(u1) ACC(u2) ACC(u3)
        }
        for (; i < degq; ++i) {
            uint4 u = f4[(size_t)qq[i] * 16 + gl];
            ACC(u)
        }
        #undef ACC
        float sc = rsqrtf((float)(full > 1 ? full : 1));
        float4 r0 = { a0 * sc, a1 * sc, a2 * sc, a3 * sc };
        float4 r1 = { a4 * sc, a5 * sc, a6 * sc, a7 * sc };
        ((float4*)out)[(size_t)node * 32 + gl * 2 + 0] = r0;
        ((float4*)out)[(size_t)node * 32 + gl * 2 + 1] = r1;
    }
    __syncthreads();

    // queue-overflow patch (expected 0 entries)
    int lc = lovf_cnt; if (lc > LOCAL_OVF) lc = LOCAL_OVF;
    for (int k = g; k < lc; k += NPP) {
        int ent = lovf[k];
        int dl = (ent >> 14) & 15;
        int s = ent & 0x3FFF;
        int full = scnt[dl] + sdeg[dl];
        float sc = rsqrtf((float)(full > 1 ? full : 1));
        uint4 u = f4[(size_t)s * 16 + gl];
        float* orow = out + (size_t)(bstart + dl) * D_FEAT + gl * 8;
        atomicAdd(&orow[0], bf_lo(u.x) * sc);
        atomicAdd(&orow[1], bf_hi(u.x) * sc);
        atomicAdd(&orow[2], bf_lo(u.y) * sc);
        atomicAdd(&orow[3], bf_hi(u.y) * sc);
        atomicAdd(&orow[4], bf_lo(u.z) * sc);
        atomicAdd(&orow[5], bf_hi(u.z) * sc);
        atomicAdd(&orow[6], bf_lo(u.w) * sc);
        atomicAdd(&orow[7], bf_hi(u.w) * sc);
    }
    // bin-cell overflow patch (expected 0 entries)
    int oc2 = sovf_cnt; if (oc2 > LOCAL_OVF) oc2 = LOCAL_OVF;
    for (int k = g; k < oc2; k += NPP) {
        int ent = sovf[k];
        int dl = (ent >> 14) & 15;
        int s = ent & 0x3FFF;
        int full = scnt[dl] + sdeg[dl];
        float sc = rsqrtf((float)(full > 1 ? full : 1));
        uint4 u = f4[(size_t)s * 16 + gl];
        float* orow = out + (size_t)(bstart + dl) * D_FEAT + gl * 8;
        atomicAdd(&orow[0], bf_lo(u.x) * sc);
        atomicAdd(&orow[1], bf_hi(u.x) * sc);
        atomicAdd(&orow[2], bf_lo(u.y) * sc);
        atomicAdd(&orow[3], bf_hi(u.y) * sc);
        atomicAdd(&orow[4], bf_lo(u.z) * sc);
        atomicAdd(&orow[5], bf_hi(u.z) * sc);
        atomicAdd(&orow[6], bf_lo(u.w) * sc);
        atomicAdd(&orow[7], bf_hi(u.w) * sc);
    }
}

// ---------------- fallback path (fp32 atomics) ----------------

__global__ void zero_kernel(float* __restrict__ out, float* __restrict__ deg,
                            int n_out, int n_deg) {
    int i = blockIdx.x * blockDim.x + threadIdx.x;
    if (i < n_out) out[i] = 0.0f;
    if (i < n_deg) deg[i] = 0.0f;
}

__global__ void scatter_kernel(const float* __restrict__ feat,
                               const int* __restrict__ src,
                               const int* __restrict__ dst,
                               float* __restrict__ out,
                               float* __restrict__ deg,
                               int n_edges) {
    long long gid = (long long)blockIdx.x * blockDim.x + threadIdx.x;
    int e = (int)(gid >> 7);
    int f = (int)(gid & 127);
    if (e >= n_edges) return;
    int s = src[e];
    int d = dst[e];
    float v = feat[(long long)s * D_FEAT + f];
    atomicAdd(&out[(long long)d * D_FEAT + f], v);
    if (f == 0) atomicAdd(&deg[d], 1.0f);
}

__global__ void norm_kernel(float* __restrict__ out, const float* __restrict__ deg,
                            int n_out) {
    int gid = blockIdx.x * blockDim.x + threadIdx.x;
    if (gid >= n_out) return;
    int i = gid >> 7;
    float dg = fmaxf(deg[i], 1.0f);
    out[gid] = out[gid] * rsqrtf(dg);
}

extern "C" void kernel_launch(void* const* d_in, const int* in_sizes, int n_in,
                              void* d_out, int out_size, void* d_ws, size_t ws_size,
                              hipStream_t stream) {
    const float* feat = (const float*)d_in[0];
    const int*   src  = (const int*)d_in[1];
    const int*   dst  = (const int*)d_in[2];
    float* out = (float*)d_out;

    const int n_edges = in_sizes[1];
    const int n_out   = out_size;            // n_nodes * 128
    const int n_nodes = n_out / D_FEAT;

    int npart  = (n_nodes + NPP - 1) / NPP;
    int nblk   = (n_edges + EPB - 1) / EPB;
    int npacks = n_out / 4;

    // ws (ints): povf_cnt[nblk] | povf[nblk*OVF_PB] | pad | bins[nblk*npart*PCAP]
    //            | fbf[n_out/2]
    size_t head = ((size_t)nblk + (size_t)nblk * OVF_PB + 3) & ~(size_t)3;
    size_t bins_ints = (size_t)nblk * npart * PCAP;
    size_t fbf_off = (head + bins_ints + 3) & ~(size_t)3;
    size_t need = (fbf_off + (size_t)n_out / 2) * sizeof(int);

    if (ws_size >= need && npart <= MAX_NPART && n_nodes <= 16384) {
        int* povf_cnt = (int*)d_ws;
        int* povf     = povf_cnt + nblk;
        u32* bins     = (u32*)d_ws + head;
        u32* fbf      = (u32*)d_ws + fbf_off;

        bin_kernel<<<nblk, BIN_THREADS, 0, stream>>>(
            src, dst, feat, fbf, povf_cnt, povf, bins,
            n_edges, npart, nblk, npacks);
        gather_kernel<<<npart, 256, 0, stream>>>(
            fbf, bins, povf_cnt, povf, out, n_nodes, npart, nblk);
    } else {
        float* deg = (float*)d_ws;
        {
            int threads = 256;
            int blocks = (n_out + threads - 1) / threads;
            zero_kernel<<<blocks, threads, 0, stream>>>(out, deg, n_out, n_nodes);
        }
        {
            long long total = (long long)n_edges * D_FEAT;
            int threads = 256;
            int blocks = (int)((total + threads - 1) / threads);
            scatter_kernel<<<blocks, threads, 0, stream>>>(feat, src, dst, out, deg, n_edges);
        }
        {
            int threads = 256;
            int blocks = (n_out + threads - 1) / threads;
            norm_kernel<<<blocks, threads, 0, stream>>>(out, deg, n_out);
        }
    }
}